// Round 5
// baseline (313.355 us; speedup 1.0000x reference)
//
#include <hip/hip_runtime.h>

// HashTable voxel-corner feature gather.
// coords: (4096,128,3) f32 in [0,1); table: (2^22, 16) f32; out: (4096,128,16) f32.
//
// CORRECTNESS-CRITICAL hash semantics (reverse-engineered from absmax
// fingerprints; golden outputs follow the original torch module):
//  * voxel index: torch div-by-scalar is multiply-by-reciprocal:
//      bxi = floor(cx * 100.0f)            (NOT floor(cx / 0.01f)!)
//    (1/0.01 in f64 -> cast f32 == 100.0f exactly)
//  * base/voxel coords: strict f32 mul/add (separate torch kernels, no FMA):
//      bx = round(bxi * 0.01f); vx = round(bx + off)   -- NOFUSE barriers
//  * hash einsum (BLAS sgemv K=3, FMA chain, ascending c):
//      h = fma(vz, P2, fma(vy, P1, round(vx * P0)))
//  * mod 2^22 exact, trunc to int32.
// Evidence: strict-all hash -> absmax 10.5625; fma-chain + f32 div ->
// 4.1953125 (rare flips only) => rare mechanism is the division path.

#define VS 0.01f

#define NOFUSE(x) asm volatile("" : "+v"(x))

__global__ __launch_bounds__(256) void hash_gather_kernel(
    const float* __restrict__ coords,
    const float* __restrict__ table,
    float* __restrict__ out,
    int npts)
{
#pragma clang fp contract(off)
    int p = blockIdx.x * blockDim.x + threadIdx.x;
    if (p >= npts) return;

    float cx = coords[3 * p + 0];
    float cy = coords[3 * p + 1];
    float cz = coords[3 * p + 2];

    // torch reciprocal-mul division, then trunc (coords >= 0 so trunc==floor)
    float bxi = floorf(cx * 100.0f);
    float byi = floorf(cy * 100.0f);
    float bzi = floorf(cz * 100.0f);

    // base coord: strict f32 mul (int->float->*VS), protected from fusion
    float bx = bxi * VS; NOFUSE(bx);
    float by = byi * VS; NOFUSE(by);
    float bz = bzi * VS; NOFUSE(bz);

    const float P0 = 73856093.0f, P1 = 19349663.0f, P2 = 83492791.0f;

    const float ox[8] = {0.f, VS, VS, 0.f, 0.f, VS, VS, 0.f};
    const float oy[8] = {0.f, 0.f, VS, VS, 0.f, 0.f, VS, VS};
    const float oz[8] = {0.f, 0.f, 0.f, 0.f, VS, VS, VS, VS};

    const float inv_diag = 1.0f / (sqrtf(3.0f) * VS);

    int   hidx[8];
    float w[8];
#pragma unroll
    for (int k = 0; k < 8; ++k) {
        float vx = bx + ox[k]; NOFUSE(vx);   // strict add, no fma(bxi,VS,off)
        float vy = by + oy[k]; NOFUSE(vy);
        float vz = bz + oz[k]; NOFUSE(vz);

        // hash: sequential FMA chain seeded by rounded first product
        float px = vx * P0; NOFUSE(px);              // round(vx*P0)
        float h  = __builtin_fmaf(vz, P2,
                   __builtin_fmaf(vy, P1, px));      // two fused steps

        // exact mod 2^22 (h >= 0): every step exact in f32.
        float q  = truncf(h * 2.384185791015625e-07f);  // h * 2^-22 exact
        float hm = h - q * 4194304.0f;                  // exact subtraction
        hidx[k] = (int)hm;                              // trunc == astype(int32)

        float dx = cx - vx, dy = cy - vy, dz = cz - vz;
        w[k] = sqrtf(dx * dx + dy * dy + dz * dz) * inv_diag;  // loose tolerance
    }

    float4 acc0 = {0, 0, 0, 0}, acc1 = {0, 0, 0, 0},
           acc2 = {0, 0, 0, 0}, acc3 = {0, 0, 0, 0};

#pragma unroll
    for (int k = 0; k < 8; ++k) {
        const float4* row = (const float4*)(table + (size_t)hidx[k] * 16);
        float4 r0 = row[0], r1 = row[1], r2 = row[2], r3 = row[3];
        float wk = w[k];
        acc0.x += r0.x * wk; acc0.y += r0.y * wk; acc0.z += r0.z * wk; acc0.w += r0.w * wk;
        acc1.x += r1.x * wk; acc1.y += r1.y * wk; acc1.z += r1.z * wk; acc1.w += r1.w * wk;
        acc2.x += r2.x * wk; acc2.y += r2.y * wk; acc2.z += r2.z * wk; acc2.w += r2.w * wk;
        acc3.x += r3.x * wk; acc3.y += r3.y * wk; acc3.z += r3.z * wk; acc3.w += r3.w * wk;
    }

    float4* o = (float4*)(out + (size_t)p * 16);
    o[0] = acc0; o[1] = acc1; o[2] = acc2; o[3] = acc3;
}

extern "C" void kernel_launch(void* const* d_in, const int* in_sizes, int n_in,
                              void* d_out, int out_size, void* d_ws, size_t ws_size,
                              hipStream_t stream) {
    const float* coords = (const float*)d_in[0];   // (4096,128,3)
    const float* table  = (const float*)d_in[1];   // (2^22, 16)
    float* out = (float*)d_out;                    // (4096,128,16)

    int npts = in_sizes[0] / 3;                    // 524288
    int block = 256;
    int grid = (npts + block - 1) / block;         // 2048
    hash_gather_kernel<<<grid, block, 0, stream>>>(coords, table, out, npts);
}

// Round 6
// 84.403 us; speedup vs baseline: 3.7126x; 3.7126x over previous
//
#include <hip/hip_runtime.h>

// HashTable voxel-corner feature gather — quad-cooperative row loads.
// coords: (4096,128,3) f32; table: (2^22, 16) f32; out: (4096,128,16) f32.
//
// CORRECTNESS-CRITICAL hash semantics (verified passing in round 5):
//  * voxel index: torch div-by-scalar = multiply-by-reciprocal:
//      bxi = floor(cx * 100.0f)   (NOT / 0.01f)
//  * base/voxel coords: strict f32 mul/add (NOFUSE barriers block FMA)
//  * hash einsum: FMA chain  h = fma(vz,P2, fma(vy,P1, round(vx*P0)))
//  * exact mod 2^22, trunc to int32.
//
// PERF: 4 lanes per point; lane (t&3) loads 16 B of each 64 B table row so a
// lane-quad's requests are contiguous -> one coalesced 64 B transaction per
// row (round 5: 4 separate dwordx4 per row -> ~234 B fetched per 64 B row).
// 4x thread count also quadruples outstanding misses (latency hiding).

#define VS 0.01f

#define NOFUSE(x) asm volatile("" : "+v"(x))

__global__ __launch_bounds__(256) void hash_gather_kernel(
    const float* __restrict__ coords,
    const float* __restrict__ table,
    float* __restrict__ out,
    int npts)
{
#pragma clang fp contract(off)
    int t = blockIdx.x * blockDim.x + threadIdx.x;
    int p   = t >> 2;        // point index (4 lanes per point)
    int col = t & 3;         // float4 column of the 16-float row
    if (p >= npts) return;

    float cx = coords[3 * p + 0];
    float cy = coords[3 * p + 1];
    float cz = coords[3 * p + 2];

    // torch reciprocal-mul division, then floor (coords >= 0)
    float bxi = floorf(cx * 100.0f);
    float byi = floorf(cy * 100.0f);
    float bzi = floorf(cz * 100.0f);

    // base coord: strict f32 mul, protected from fusion
    float bx = bxi * VS; NOFUSE(bx);
    float by = byi * VS; NOFUSE(by);
    float bz = bzi * VS; NOFUSE(bz);

    const float P0 = 73856093.0f, P1 = 19349663.0f, P2 = 83492791.0f;

    const float ox[8] = {0.f, VS, VS, 0.f, 0.f, VS, VS, 0.f};
    const float oy[8] = {0.f, 0.f, VS, VS, 0.f, 0.f, VS, VS};
    const float oz[8] = {0.f, 0.f, 0.f, 0.f, VS, VS, VS, VS};

    const float inv_diag = 1.0f / (sqrtf(3.0f) * VS);

    int   hidx[8];
    float w[8];
#pragma unroll
    for (int k = 0; k < 8; ++k) {
        float vx = bx + ox[k]; NOFUSE(vx);   // strict add, no fma(bxi,VS,off)
        float vy = by + oy[k]; NOFUSE(vy);
        float vz = bz + oz[k]; NOFUSE(vz);

        float px = vx * P0; NOFUSE(px);              // round(vx*P0)
        float h  = __builtin_fmaf(vz, P2,
                   __builtin_fmaf(vy, P1, px));      // fused chain

        // exact mod 2^22 (h >= 0)
        float q  = truncf(h * 2.384185791015625e-07f);  // h * 2^-22, exact
        float hm = h - q * 4194304.0f;                  // exact
        hidx[k] = (int)hm;

        float dx = cx - vx, dy = cy - vy, dz = cz - vz;
        w[k] = sqrtf(dx * dx + dy * dy + dz * dz) * inv_diag;  // loose tol
    }

    // issue all 8 row-slice loads first (max memory-level parallelism)
    float4 r[8];
#pragma unroll
    for (int k = 0; k < 8; ++k) {
        r[k] = ((const float4*)(table + (size_t)hidx[k] * 16))[col];
    }

    float4 acc = {0.f, 0.f, 0.f, 0.f};
#pragma unroll
    for (int k = 0; k < 8; ++k) {
        float wk = w[k];
        acc.x += r[k].x * wk;
        acc.y += r[k].y * wk;
        acc.z += r[k].z * wk;
        acc.w += r[k].w * wk;
    }

    ((float4*)(out + (size_t)p * 16))[col] = acc;
}

extern "C" void kernel_launch(void* const* d_in, const int* in_sizes, int n_in,
                              void* d_out, int out_size, void* d_ws, size_t ws_size,
                              hipStream_t stream) {
    const float* coords = (const float*)d_in[0];   // (4096,128,3)
    const float* table  = (const float*)d_in[1];   // (2^22, 16)
    float* out = (float*)d_out;                    // (4096,128,16)

    int npts = in_sizes[0] / 3;                    // 524288
    long long nthreads = (long long)npts * 4;      // 2,097,152
    int block = 256;
    int grid = (int)((nthreads + block - 1) / block);  // 8192
    hash_gather_kernel<<<grid, block, 0, stream>>>(coords, table, out, npts);
}